// Round 8
// baseline (167.139 us; speedup 1.0000x reference)
//
#include <hip/hip_runtime.h>
#include <hip/hip_bf16.h>

// ---------------------------------------------------------------------------
// GCN classifier.  R1: multi-block scan.  R2: agg unroll x4.  R3: bf16
// activations + 64-row GEMM tiles.  R4: bucketed counting-sort CSR build.
// R5: 2-stage pool + init kernel (memset removed from graph).
// R6: MFMA GEMM (v_mfma_f32_16x16x32_bf16): weights pre-transposed+bf16
//     (Wt[n][k]), staged in LDS with XOR swizzle; A-frags straight from
//     global (emb-gather fused for layer 1). Old VALU gemm was 42us at 36%
//     VALUBusy; MFMA math is ~1us, kernel becomes L2/HBM-bound.
// ---------------------------------------------------------------------------

typedef unsigned int uint;
typedef unsigned short ushort;
typedef __attribute__((ext_vector_type(8))) short bf16x8;
typedef __attribute__((ext_vector_type(4))) float f32x4;

__device__ inline float bf_lo(uint u) { return __uint_as_float(u << 16); }
__device__ inline float bf_hi(uint u) { return __uint_as_float(u & 0xffff0000u); }
__device__ inline ushort f2bf(float f) {           // round-to-nearest-even
    uint u = __float_as_uint(f);
    return (ushort)((u + 0x7fffu + ((u >> 16) & 1u)) >> 16);
}
__device__ inline uint pack2bf(float a, float b) {
    return (uint)f2bf(a) | ((uint)f2bf(b) << 16);
}

#define EPB 2048   // edges per block in bucketing kernels

// ---- 0) zero the accumulator region (bcnt | gcnt | pooled) ----------------
__global__ __launch_bounds__(256) void init_kernel(int4* __restrict__ z, int n4) {
    int i = blockIdx.x * blockDim.x + threadIdx.x;
    if (i < n4) z[i] = make_int4(0, 0, 0, 0);
}

// ---- 0b) weight convert: W[k][n] f32 -> Wt[n][k] bf16 ---------------------
__global__ __launch_bounds__(256) void convert_w(const float* __restrict__ Win,
                                                 ushort* __restrict__ Wt) {
    int i = blockIdx.x * 256 + threadIdx.x;      // 0..16383
    int nn = i >> 7, k = i & 127;
    Wt[i] = f2bf(Win[k * 128 + nn]);
}

// ---- 1) per-bucket histogram (LDS-aggregated) -----------------------------
__global__ __launch_bounds__(256) void bucket_hist(const int* __restrict__ dst,
                                                   int* __restrict__ bcnt, int E, int NB) {
    __shared__ int lh[256];
    const int t = threadIdx.x;
    lh[t] = 0;
    __syncthreads();
    const int base = blockIdx.x * EPB;
    const int end  = min(E, base + EPB);
    for (int i = base + t; i < end; i += 256)
        atomicAdd(&lh[((uint)dst[i]) >> 8], 1);
    __syncthreads();
    if (t < NB && lh[t]) atomicAdd(&bcnt[t], lh[t]);
}

// ---- 2) scan bucket counts -> boff[0..NB]; init bcur ----------------------
__global__ __launch_bounds__(256) void bucket_scan(const int* __restrict__ bcnt,
                                                   int* __restrict__ boff,
                                                   int* __restrict__ bcur, int NB) {
    __shared__ int ls[256];
    const int t = threadIdx.x;
    int v = (t < NB) ? bcnt[t] : 0;
    ls[t] = v;
    __syncthreads();
    for (int off = 1; off < 256; off <<= 1) {
        int x = (t >= off) ? ls[t - off] : 0;
        __syncthreads();
        ls[t] += x;
        __syncthreads();
    }
    int excl = ls[t] - v;
    if (t <= NB) {
        int o = (t < NB) ? excl : ls[255];
        boff[t] = o;
        if (t < NB) bcur[t] = o;
    }
    if (t == 255 && NB < 255) boff[NB] = ls[255];
}

// ---- 3) scatter edges into bucket-staged array (block-local presort) ------
__global__ __launch_bounds__(256) void bucket_scatter(const int* __restrict__ src,
                                                      const int* __restrict__ dst,
                                                      int* __restrict__ bcur,
                                                      uint* __restrict__ bstage,
                                                      int E, int NB) {
    __shared__ int lh[256];
    __shared__ int lbase[257];
    __shared__ int gbase[256];
    __shared__ int lcur[256];
    __shared__ uint stage[EPB];
    const int t = threadIdx.x;
    const int base = blockIdx.x * EPB;
    const int end  = min(E, base + EPB);
    const int tot  = end - base;

    lh[t] = 0;
    __syncthreads();

    uint pk[8]; int bk[8]; int cnt = 0;
    for (int i = base + t; i < end; i += 256) {
        int s = src[i];
        uint d = (uint)dst[i];
        bk[cnt] = (int)(d >> 8);
        pk[cnt] = (uint)s | ((d & 255u) << 24);
        atomicAdd(&lh[bk[cnt]], 1);
        ++cnt;
    }
    __syncthreads();

    if (t < NB && lh[t]) gbase[t] = atomicAdd(&bcur[t], lh[t]);
    {
        __shared__ int ls[256];
        int v = lh[t];
        ls[t] = v;
        __syncthreads();
        for (int off = 1; off < 256; off <<= 1) {
            int x = (t >= off) ? ls[t - off] : 0;
            __syncthreads();
            ls[t] += x;
            __syncthreads();
        }
        lbase[t] = ls[t] - v;
        if (t == 255) lbase[256] = ls[255];
        lcur[t] = 0;
    }
    __syncthreads();

    for (int j = 0; j < cnt; ++j) {
        int p = lbase[bk[j]] + atomicAdd(&lcur[bk[j]], 1);
        stage[p] = pk[j];
    }
    __syncthreads();

    for (int i = t; i < tot; i += 256) {
        int lo = 0, hi = 256;
        while (lo + 1 < hi) {
            int mid = (lo + hi) >> 1;
            if (lbase[mid] <= i) lo = mid; else hi = mid;
        }
        bstage[gbase[lo] + (i - lbase[lo])] = stage[i];
    }
}

// ---- 4) per-bucket: node hist -> dis + rowptr (coalesced), then CSR -------
__global__ __launch_bounds__(256) void csr_build(const uint* __restrict__ bstage,
                                                 const int* __restrict__ boff,
                                                 float* __restrict__ dis,
                                                 int* __restrict__ rowptr,
                                                 int* __restrict__ csr,
                                                 int N, int NB, int E) {
    __shared__ int lh[256];
    __shared__ int ls[256];
    __shared__ int lbase[256];
    __shared__ int lcur[256];
    const int b = blockIdx.x;
    const int t = threadIdx.x;
    const int base  = boff[b];
    const int cntb  = boff[b + 1] - base;
    const int n0    = b << 8;
    const int nn    = min(256, N - n0);

    lh[t] = 0;
    __syncthreads();
    for (int i = t; i < cntb; i += 256)
        atomicAdd(&lh[bstage[base + i] >> 24], 1);
    __syncthreads();

    const int v = lh[t];
    ls[t] = v;
    __syncthreads();
    for (int off = 1; off < 256; off <<= 1) {
        int x = (t >= off) ? ls[t - off] : 0;
        __syncthreads();
        ls[t] += x;
        __syncthreads();
    }
    lbase[t] = ls[t] - v;
    lcur[t] = 0;
    if (t < nn) {
        dis[n0 + t]    = rsqrtf((float)v + 1.0f);
        rowptr[n0 + t] = base + lbase[t];
    }
    if (b == NB - 1 && t == 0) rowptr[N] = E;
    __syncthreads();

    for (int i = t; i < cntb; i += 256) {
        uint e = bstage[base + i];
        int dl = (int)(e >> 24);
        int pos = base + lbase[dl] + atomicAdd(&lcur[dl], 1);
        csr[pos] = (int)(e & 0xFFFFFFu);
    }
}

// ---------------------------------------------------------------------------
// MFMA GEMM: Out_bf16[n,128] = A[n,128] @ W[128,128]
// Wt: bf16, pre-transposed [n(out col)][k].  A: bf16 rows (or emb-gather if
// GATHER).  Block = 256 thr = 4 waves, 128 rows/block, wave = 32 rows.
// LDS: Wt swizzled (byte ^= (row&7)<<4), ds_read_b128 conflict-free (2/bank).
// Frag layouts (16x16x32): A/B lane l -> (m|n = l&15, k = (l>>4)*8+j);
// C/D lane l, reg r -> (col = l&15, row = (l>>4)*4 + r).
// ---------------------------------------------------------------------------
template<bool GATHER>
__global__ __launch_bounds__(256) void gemm_mfma(const ushort* __restrict__ Xbf,
                                                 const int* __restrict__ tokens,
                                                 const float* __restrict__ emb,
                                                 const ushort* __restrict__ Wt,
                                                 ushort* __restrict__ Out, int n) {
    __shared__ ushort wl[128 * 128];   // 32KB, swizzled
    const int tid = threadIdx.x;

    // stage Wt -> LDS (coalesced global uint4, swizzled b128 writes)
    {
        const int row  = tid >> 1;            // 0..127 (output col n)
        const int half = tid & 1;
        const int base = row * 256 + half * 128;   // byte offset in Wt
#pragma unroll
        for (int i = 0; i < 8; ++i) {
            int off = base + i * 16;
            uint4 v = *(const uint4*)((const char*)Wt + off);
            int swz = off ^ ((row & 7) << 4);
            *(uint4*)((char*)wl + swz) = v;
        }
    }
    __syncthreads();

    const int w  = tid >> 6;          // wave 0..3
    const int l  = tid & 63;
    const int lr = l & 15;
    const int lg = l >> 4;            // 0..3
    const int rowBase = blockIdx.x * 128 + w * 32;

    f32x4 acc[2][8];
#pragma unroll
    for (int s = 0; s < 2; ++s)
#pragma unroll
        for (int ct = 0; ct < 8; ++ct) acc[s][ct] = (f32x4){0.f, 0.f, 0.f, 0.f};

    // A fragments: strip s covers rows rowBase + s*16 + (l&15)
    bf16x8 afrag[2][4];
#pragma unroll
    for (int s = 0; s < 2; ++s) {
        const int row = rowBase + s * 16 + lr;
        if (row < n) {
            if (GATHER) {
                const int tok = tokens[row];
                if (tok != 0) {
                    const float* ep = emb + (size_t)tok * 128;
#pragma unroll
                    for (int kk = 0; kk < 4; ++kk) {
                        const float* q = ep + kk * 32 + lg * 8;
                        float4 lo = *(const float4*)q;
                        float4 hi = *(const float4*)(q + 4);
                        uint4 pk;
                        pk.x = pack2bf(lo.x, lo.y); pk.y = pack2bf(lo.z, lo.w);
                        pk.z = pack2bf(hi.x, hi.y); pk.w = pack2bf(hi.z, hi.w);
                        union { uint4 u; bf16x8 b; } c; c.u = pk;
                        afrag[s][kk] = c.b;
                    }
                } else {
#pragma unroll
                    for (int kk = 0; kk < 4; ++kk) afrag[s][kk] = (bf16x8){0,0,0,0,0,0,0,0};
                }
            } else {
                const ushort* xp = Xbf + (size_t)row * 128;
#pragma unroll
                for (int kk = 0; kk < 4; ++kk)
                    afrag[s][kk] = *(const bf16x8*)(xp + kk * 32 + lg * 8);
            }
        } else {
#pragma unroll
            for (int kk = 0; kk < 4; ++kk) afrag[s][kk] = (bf16x8){0,0,0,0,0,0,0,0};
        }
    }

    // MFMA main: 8 col tiles x 4 k-chunks x 2 strips
#pragma unroll
    for (int ct = 0; ct < 8; ++ct) {
#pragma unroll
        for (int kk = 0; kk < 4; ++kk) {
            const int nrow = ct * 16 + lr;
            int off = nrow * 256 + kk * 64 + lg * 16;
            off ^= ((nrow & 7) << 4);
            bf16x8 b = *(const bf16x8*)((const char*)wl + off);
            acc[0][ct] = __builtin_amdgcn_mfma_f32_16x16x32_bf16(afrag[0][kk], b, acc[0][ct], 0, 0, 0);
            acc[1][ct] = __builtin_amdgcn_mfma_f32_16x16x32_bf16(afrag[1][kk], b, acc[1][ct], 0, 0, 0);
        }
    }

    // store C (bf16): lane l, reg r -> row = base + s*16 + lg*4 + r, col = ct*16 + lr
#pragma unroll
    for (int s = 0; s < 2; ++s) {
#pragma unroll
        for (int r = 0; r < 4; ++r) {
            const int row = rowBase + s * 16 + lg * 4 + r;
            if (row < n) {
                ushort* op = Out + (size_t)row * 128 + lr;
#pragma unroll
                for (int ct = 0; ct < 8; ++ct)
                    op[ct * 16] = f2bf(acc[s][ct][r]);
            }
        }
    }
}

// ---------------------------------------------------------------------------
// Aggregation over bf16 H.
// ---------------------------------------------------------------------------
template<bool OUT_BF16>
__global__ __launch_bounds__(256) void aggregate_kernel(const ushort* __restrict__ H,
                                                        const float* __restrict__ dis,
                                                        const int* __restrict__ rowptr,
                                                        const int* __restrict__ csr_src,
                                                        const float* __restrict__ bias,
                                                        void* __restrict__ OutV, int n) {
    const int g = threadIdx.x >> 4;
    const int l = threadIdx.x & 15;
    const int node = blockIdx.x * 16 + g;
    if (node >= n) return;

    const float dn = dis[node];
    const uint4 hq = *(const uint4*)(H + (size_t)node * 128 + l * 8);
    const int e0 = rowptr[node];
    const int e1 = rowptr[node + 1];

    float s0_ = 0.f, s1_ = 0.f, s2_ = 0.f, s3_ = 0.f,
          s4_ = 0.f, s5_ = 0.f, s6_ = 0.f, s7_ = 0.f;

    int e = e0;
    for (; e + 4 <= e1; e += 4) {
        const int a0 = csr_src[e + 0];
        const int a1 = csr_src[e + 1];
        const int a2 = csr_src[e + 2];
        const int a3 = csr_src[e + 3];
        const float w0 = dis[a0];
        const float w1 = dis[a1];
        const float w2 = dis[a2];
        const float w3 = dis[a3];
        const uint4 h0 = *(const uint4*)(H + (size_t)a0 * 128 + l * 8);
        const uint4 h1 = *(const uint4*)(H + (size_t)a1 * 128 + l * 8);
        const uint4 h2 = *(const uint4*)(H + (size_t)a2 * 128 + l * 8);
        const uint4 h3 = *(const uint4*)(H + (size_t)a3 * 128 + l * 8);
        s0_ += bf_lo(h0.x)*w0 + bf_lo(h1.x)*w1 + bf_lo(h2.x)*w2 + bf_lo(h3.x)*w3;
        s1_ += bf_hi(h0.x)*w0 + bf_hi(h1.x)*w1 + bf_hi(h2.x)*w2 + bf_hi(h3.x)*w3;
        s2_ += bf_lo(h0.y)*w0 + bf_lo(h1.y)*w1 + bf_lo(h2.y)*w2 + bf_lo(h3.y)*w3;
        s3_ += bf_hi(h0.y)*w0 + bf_hi(h1.y)*w1 + bf_hi(h2.y)*w2 + bf_hi(h3.y)*w3;
        s4_ += bf_lo(h0.z)*w0 + bf_lo(h1.z)*w1 + bf_lo(h2.z)*w2 + bf_lo(h3.z)*w3;
        s5_ += bf_hi(h0.z)*w0 + bf_hi(h1.z)*w1 + bf_hi(h2.z)*w2 + bf_hi(h3.z)*w3;
        s6_ += bf_lo(h0.w)*w0 + bf_lo(h1.w)*w1 + bf_lo(h2.w)*w2 + bf_lo(h3.w)*w3;
        s7_ += bf_hi(h0.w)*w0 + bf_hi(h1.w)*w1 + bf_hi(h2.w)*w2 + bf_hi(h3.w)*w3;
    }
    for (; e < e1; ++e) {
        const int a = csr_src[e];
        const float w = dis[a];
        const uint4 h = *(const uint4*)(H + (size_t)a * 128 + l * 8);
        s0_ += bf_lo(h.x)*w; s1_ += bf_hi(h.x)*w;
        s2_ += bf_lo(h.y)*w; s3_ += bf_hi(h.y)*w;
        s4_ += bf_lo(h.z)*w; s5_ += bf_hi(h.z)*w;
        s6_ += bf_lo(h.w)*w; s7_ += bf_hi(h.w)*w;
    }

    const float self = dn * dn;
    const float4 bA = *(const float4*)&bias[l * 8];
    const float4 bB = *(const float4*)&bias[l * 8 + 4];
    float o0 = fmaxf(s0_ * dn + bf_lo(hq.x) * self + bA.x, 0.0f);
    float o1 = fmaxf(s1_ * dn + bf_hi(hq.x) * self + bA.y, 0.0f);
    float o2 = fmaxf(s2_ * dn + bf_lo(hq.y) * self + bA.z, 0.0f);
    float o3 = fmaxf(s3_ * dn + bf_hi(hq.y) * self + bA.w, 0.0f);
    float o4 = fmaxf(s4_ * dn + bf_lo(hq.z) * self + bB.x, 0.0f);
    float o5 = fmaxf(s5_ * dn + bf_hi(hq.z) * self + bB.y, 0.0f);
    float o6 = fmaxf(s6_ * dn + bf_lo(hq.w) * self + bB.z, 0.0f);
    float o7 = fmaxf(s7_ * dn + bf_hi(hq.w) * self + bB.w, 0.0f);

    if (OUT_BF16) {
        uint4 o;
        o.x = pack2bf(o0, o1); o.y = pack2bf(o2, o3);
        o.z = pack2bf(o4, o5); o.w = pack2bf(o6, o7);
        *(uint4*)((ushort*)OutV + (size_t)node * 128 + l * 8) = o;
    } else {
        float4 oa, ob;
        oa.x = o0; oa.y = o1; oa.z = o2; oa.w = o3;
        ob.x = o4; ob.y = o5; ob.z = o6; ob.w = o7;
        *(float4*)((float*)OutV + (size_t)node * 128 + l * 8)     = oa;
        *(float4*)((float*)OutV + (size_t)node * 128 + l * 8 + 4) = ob;
    }
}

// ---------------------------------------------------------------------------
// Pool stage 1: segmented column-sum (register accumulate, flush per segment)
// ---------------------------------------------------------------------------
__global__ __launch_bounds__(256) void pool_partial(const float* __restrict__ X,
                                                    const int* __restrict__ batch,
                                                    float* __restrict__ pooled,
                                                    int* __restrict__ gcnt, int n) {
    const int grp = threadIdx.x >> 7;
    const int t   = threadIdx.x & 127;
    const int r0  = blockIdx.x * 128 + grp * 64;
    if (r0 >= n) return;
    const int r1 = min(r0 + 64, n);

    int gcur = batch[r0];
    float sum = 0.0f;
    int cnt = 0;
    for (int r = r0; r < r1; ++r) {
        const int g = batch[r];
        const float v = X[(size_t)r * 128 + t];
        if (g != gcur) {
            atomicAdd(&pooled[(size_t)gcur * 128 + t], sum);
            if (t == 0) atomicAdd(&gcnt[gcur], cnt);
            sum = 0.0f; cnt = 0; gcur = g;
        }
        sum += v; ++cnt;
    }
    atomicAdd(&pooled[(size_t)gcur * 128 + t], sum);
    if (t == 0) atomicAdd(&gcnt[gcur], cnt);
}

// ---------------------------------------------------------------------------
// Pool stage 2: divide by count + 128x10 linear.
// ---------------------------------------------------------------------------
__global__ __launch_bounds__(128) void pool_finalize(const float* __restrict__ pooled,
                                                     const int* __restrict__ gcnt,
                                                     const float* __restrict__ lw,
                                                     const float* __restrict__ lb,
                                                     float* __restrict__ out) {
    const int g = blockIdx.x;
    const int t = threadIdx.x;
    __shared__ float pl[128];
    const float c = fmaxf((float)gcnt[g], 1.0f);
    pl[t] = pooled[(size_t)g * 128 + t] / c;
    __syncthreads();
    if (t < 10) {
        float acc = lb[t];
#pragma unroll 16
        for (int d = 0; d < 128; ++d) acc += pl[d] * lw[d * 10 + t];
        out[g * 10 + t] = acc;
    }
}

// ---------------------------------------------------------------------------
extern "C" void kernel_launch(void* const* d_in, const int* in_sizes, int n_in,
                              void* d_out, int out_size, void* d_ws, size_t ws_size,
                              hipStream_t stream) {
    const int*   tokens = (const int*)d_in[0];
    const int*   eidx   = (const int*)d_in[1];
    const int*   batch  = (const int*)d_in[2];
    const float* emb    = (const float*)d_in[3];
    const float* w1     = (const float*)d_in[4];
    const float* b1     = (const float*)d_in[5];
    const float* w2     = (const float*)d_in[6];
    const float* b2     = (const float*)d_in[7];
    const float* lw     = (const float*)d_in[8];
    const float* lbv    = (const float*)d_in[9];

    const int N = in_sizes[0];
    const int E = in_sizes[1] / 2;
    const int G = out_size / 10;
    const int* src = eidx;
    const int* dst = eidx + E;
    const int NB = (N + 255) >> 8;

    char* p = (char*)d_ws;
    auto alloc = [&](size_t bytes) { void* r = (void*)p; p += (bytes + 255) & ~(size_t)255; return r; };
    float*  dis    = (float*)alloc((size_t)N * 4);
    int*    rowptr = (int*)  alloc(((size_t)N + 1) * 4);
    int*    zreg   = (int*)  alloc((size_t)(1024 + (size_t)G * 128) * 4);
    int*    bcnt   = zreg;
    int*    gcnt   = zreg + 512;
    float*  pooled = (float*)(zreg + 1024);
    int*    boff   = (int*)  alloc(260 * 4);
    int*    bcur   = (int*)  alloc(260 * 4);
    uint*   bstage = (uint*) alloc((size_t)E * 4);
    int*    csr    = (int*)  alloc((size_t)E * 4);
    ushort* W1t    = (ushort*)alloc(16384 * 2);
    ushort* W2t    = (ushort*)alloc(16384 * 2);
    ushort* A      = (ushort*)alloc((size_t)N * 128 * 2);   // H (bf16)
    ushort* B      = (ushort*)alloc((size_t)N * 128 * 2);   // X2 (bf16)
    float*  C      = (float*) alloc((size_t)N * 128 * 4);   // X3 (f32)

    const int ZN4 = (1024 + G * 128) / 4;
    const int EB  = (E + EPB - 1) / EPB;

    init_kernel   <<<(ZN4 + 255) / 256, 256, 0, stream>>>((int4*)zreg, ZN4);
    convert_w     <<<64, 256, 0, stream>>>(w1, W1t);
    convert_w     <<<64, 256, 0, stream>>>(w2, W2t);
    bucket_hist   <<<EB, 256, 0, stream>>>(dst, bcnt, E, NB);
    bucket_scan   <<<1, 256, 0, stream>>>(bcnt, boff, bcur, NB);
    bucket_scatter<<<EB, 256, 0, stream>>>(src, dst, bcur, bstage, E, NB);
    csr_build     <<<NB, 256, 0, stream>>>(bstage, boff, dis, rowptr, csr, N, NB, E);

    // layer 1: H = bf16(emb[tokens]) @ W1 ; X2 = relu(agg(H)+b1) (bf16)
    gemm_mfma<true><<<(N + 127) / 128, 256, 0, stream>>>(nullptr, tokens, emb, W1t, A, N);
    aggregate_kernel<true><<<(N + 15) / 16, 256, 0, stream>>>(A, dis, rowptr, csr, b1, B, N);

    // layer 2: H2 = X2 @ W2 ; X3 = relu(agg(H2)+b2) (f32)
    gemm_mfma<false><<<(N + 127) / 128, 256, 0, stream>>>(B, nullptr, nullptr, W2t, A, N);
    aggregate_kernel<false><<<(N + 15) / 16, 256, 0, stream>>>(A, dis, rowptr, csr, b2, C, N);

    // mean pool + classifier
    pool_partial <<<(N + 127) / 128, 256, 0, stream>>>(C, batch, pooled, gcnt, N);
    pool_finalize<<<G, 128, 0, stream>>>(pooled, gcnt, lw, lbv, (float*)d_out);
}

// Round 9
// 155.054 us; speedup vs baseline: 1.0779x; 1.0779x over previous
//
#include <hip/hip_runtime.h>
#include <hip/hip_bf16.h>

// ---------------------------------------------------------------------------
// GCN classifier.  R1: multi-block scan.  R2: agg unroll x4.  R3: bf16
// activations + 64-row GEMM tiles.  R4: bucketed counting-sort CSR build.
// R5: 2-stage pool + init kernel.  R6: MFMA GEMM (16x16x32 bf16).
// R9: fixed-capacity buckets (CAP=8192 >> Poisson(4082) tail) -> hist+scan
//     kernels dropped, csr_build emits rbeg/rend; aggregate unroll 8 (deeper
//     memory-level parallelism); X3 bf16 (agg2 writes bf16 into B, pool reads
//     bf16); convert_w merged into one launch.
// ---------------------------------------------------------------------------

typedef unsigned int uint;
typedef unsigned short ushort;
typedef __attribute__((ext_vector_type(8))) short bf16x8;
typedef __attribute__((ext_vector_type(4))) float f32x4;

__device__ inline float bf_lo(uint u) { return __uint_as_float(u << 16); }
__device__ inline float bf_hi(uint u) { return __uint_as_float(u & 0xffff0000u); }
__device__ inline float bf1(ushort u) { return __uint_as_float(((uint)u) << 16); }
__device__ inline ushort f2bf(float f) {           // round-to-nearest-even
    uint u = __float_as_uint(f);
    return (ushort)((u + 0x7fffu + ((u >> 16) & 1u)) >> 16);
}
__device__ inline uint pack2bf(float a, float b) {
    return (uint)f2bf(a) | ((uint)f2bf(b) << 16);
}

#define EPB 2048   // edges per block in bucketing kernels
#define CAP 8192   // per-bucket staged-edge capacity (avg 4082, Poisson tail ~0)

// ---- 0) zero the accumulator region (bcur | gcnt | pooled) ----------------
__global__ __launch_bounds__(256) void init_kernel(int4* __restrict__ z, int n4) {
    int i = blockIdx.x * blockDim.x + threadIdx.x;
    if (i < n4) z[i] = make_int4(0, 0, 0, 0);
}

// ---- 0b) weight convert: W[k][n] f32 -> Wt[n][k] bf16 (both weights) ------
__global__ __launch_bounds__(256) void convert_w(const float* __restrict__ W1,
                                                 const float* __restrict__ W2,
                                                 ushort* __restrict__ W1t,
                                                 ushort* __restrict__ W2t) {
    int i = blockIdx.x * 256 + threadIdx.x;      // 0..32767
    const float* Ws = (i < 16384) ? W1 : W2;
    ushort* Wd      = (i < 16384) ? W1t : W2t;
    int j = i & 16383;
    int nn = j >> 7, k = j & 127;
    Wd[j] = f2bf(Ws[k * 128 + nn]);
}

// ---- 1) scatter edges into fixed-capacity bucket regions (LDS presort) ----
__global__ __launch_bounds__(256) void bucket_scatter(const int* __restrict__ src,
                                                      const int* __restrict__ dst,
                                                      int* __restrict__ bcur,
                                                      uint* __restrict__ bstage,
                                                      int E, int NB) {
    __shared__ int lh[256];
    __shared__ int lbase[257];
    __shared__ int gbase[256];
    __shared__ int lcur[256];
    __shared__ uint stage[EPB];
    const int t = threadIdx.x;
    const int base = blockIdx.x * EPB;
    const int end  = min(E, base + EPB);
    const int tot  = end - base;

    lh[t] = 0;
    __syncthreads();

    uint pk[8]; int bk[8]; int cnt = 0;
    for (int i = base + t; i < end; i += 256) {
        int s = src[i];
        uint d = (uint)dst[i];
        bk[cnt] = (int)(d >> 8);
        pk[cnt] = (uint)s | ((d & 255u) << 24);
        atomicAdd(&lh[bk[cnt]], 1);
        ++cnt;
    }
    __syncthreads();

    // reserve a run inside bucket's fixed region
    if (t < NB && lh[t]) gbase[t] = t * CAP + atomicAdd(&bcur[t], lh[t]);
    {
        __shared__ int ls[256];
        int v = lh[t];
        ls[t] = v;
        __syncthreads();
        for (int off = 1; off < 256; off <<= 1) {
            int x = (t >= off) ? ls[t - off] : 0;
            __syncthreads();
            ls[t] += x;
            __syncthreads();
        }
        lbase[t] = ls[t] - v;
        if (t == 255) lbase[256] = ls[255];
        lcur[t] = 0;
    }
    __syncthreads();

    for (int j = 0; j < cnt; ++j) {
        int p = lbase[bk[j]] + atomicAdd(&lcur[bk[j]], 1);
        stage[p] = pk[j];
    }
    __syncthreads();

    for (int i = t; i < tot; i += 256) {
        int lo = 0, hi = 256;
        while (lo + 1 < hi) {
            int mid = (lo + hi) >> 1;
            if (lbase[mid] <= i) lo = mid; else hi = mid;
        }
        bstage[gbase[lo] + (i - lbase[lo])] = stage[i];
    }
}

// ---- 2) per-bucket: node hist -> dis + rbeg/rend (coalesced), then CSR ----
__global__ __launch_bounds__(256) void csr_build(const uint* __restrict__ bstage,
                                                 const int* __restrict__ bcur,
                                                 float* __restrict__ dis,
                                                 int* __restrict__ rbeg,
                                                 int* __restrict__ rend,
                                                 int* __restrict__ csr,
                                                 int N, int NB) {
    __shared__ int lh[256];
    __shared__ int ls[256];
    __shared__ int lbase[256];
    __shared__ int lcur[256];
    const int b = blockIdx.x;
    const int t = threadIdx.x;
    const int base  = b * CAP;
    const int cntb  = bcur[b];
    const int n0    = b << 8;
    const int nn    = min(256, N - n0);

    lh[t] = 0;
    __syncthreads();
    for (int i = t; i < cntb; i += 256)
        atomicAdd(&lh[bstage[base + i] >> 24], 1);
    __syncthreads();

    const int v = lh[t];
    ls[t] = v;
    __syncthreads();
    for (int off = 1; off < 256; off <<= 1) {
        int x = (t >= off) ? ls[t - off] : 0;
        __syncthreads();
        ls[t] += x;
        __syncthreads();
    }
    lbase[t] = ls[t] - v;
    lcur[t] = 0;
    if (t < nn) {
        dis[n0 + t]  = rsqrtf((float)v + 1.0f);
        rbeg[n0 + t] = base + lbase[t];
        rend[n0 + t] = base + lbase[t] + v;
    }
    __syncthreads();

    for (int i = t; i < cntb; i += 256) {
        uint e = bstage[base + i];
        int dl = (int)(e >> 24);
        int pos = base + lbase[dl] + atomicAdd(&lcur[dl], 1);
        csr[pos] = (int)(e & 0xFFFFFFu);
    }
}

// ---------------------------------------------------------------------------
// MFMA GEMM: Out_bf16[n,128] = A[n,128] @ W[128,128]
// Wt: bf16, pre-transposed [n(out col)][k].  Block = 4 waves, 128 rows.
// ---------------------------------------------------------------------------
template<bool GATHER>
__global__ __launch_bounds__(256) void gemm_mfma(const ushort* __restrict__ Xbf,
                                                 const int* __restrict__ tokens,
                                                 const float* __restrict__ emb,
                                                 const ushort* __restrict__ Wt,
                                                 ushort* __restrict__ Out, int n) {
    __shared__ ushort wl[128 * 128];   // 32KB, swizzled
    const int tid = threadIdx.x;

    {
        const int row  = tid >> 1;
        const int half = tid & 1;
        const int base = row * 256 + half * 128;
#pragma unroll
        for (int i = 0; i < 8; ++i) {
            int off = base + i * 16;
            uint4 v = *(const uint4*)((const char*)Wt + off);
            int swz = off ^ ((row & 7) << 4);
            *(uint4*)((char*)wl + swz) = v;
        }
    }
    __syncthreads();

    const int w  = tid >> 6;
    const int l  = tid & 63;
    const int lr = l & 15;
    const int lg = l >> 4;
    const int rowBase = blockIdx.x * 128 + w * 32;

    f32x4 acc[2][8];
#pragma unroll
    for (int s = 0; s < 2; ++s)
#pragma unroll
        for (int ct = 0; ct < 8; ++ct) acc[s][ct] = (f32x4){0.f, 0.f, 0.f, 0.f};

    bf16x8 afrag[2][4];
#pragma unroll
    for (int s = 0; s < 2; ++s) {
        const int row = rowBase + s * 16 + lr;
        if (row < n) {
            if (GATHER) {
                const int tok = tokens[row];
                if (tok != 0) {
                    const float* ep = emb + (size_t)tok * 128;
#pragma unroll
                    for (int kk = 0; kk < 4; ++kk) {
                        const float* q = ep + kk * 32 + lg * 8;
                        float4 lo = *(const float4*)q;
                        float4 hi = *(const float4*)(q + 4);
                        uint4 pk;
                        pk.x = pack2bf(lo.x, lo.y); pk.y = pack2bf(lo.z, lo.w);
                        pk.z = pack2bf(hi.x, hi.y); pk.w = pack2bf(hi.z, hi.w);
                        union { uint4 u; bf16x8 b; } c; c.u = pk;
                        afrag[s][kk] = c.b;
                    }
                } else {
#pragma unroll
                    for (int kk = 0; kk < 4; ++kk) afrag[s][kk] = (bf16x8){0,0,0,0,0,0,0,0};
                }
            } else {
                const ushort* xp = Xbf + (size_t)row * 128;
#pragma unroll
                for (int kk = 0; kk < 4; ++kk)
                    afrag[s][kk] = *(const bf16x8*)(xp + kk * 32 + lg * 8);
            }
        } else {
#pragma unroll
            for (int kk = 0; kk < 4; ++kk) afrag[s][kk] = (bf16x8){0,0,0,0,0,0,0,0};
        }
    }

#pragma unroll
    for (int ct = 0; ct < 8; ++ct) {
#pragma unroll
        for (int kk = 0; kk < 4; ++kk) {
            const int nrow = ct * 16 + lr;
            int off = nrow * 256 + kk * 64 + lg * 16;
            off ^= ((nrow & 7) << 4);
            bf16x8 b = *(const bf16x8*)((const char*)wl + off);
            acc[0][ct] = __builtin_amdgcn_mfma_f32_16x16x32_bf16(afrag[0][kk], b, acc[0][ct], 0, 0, 0);
            acc[1][ct] = __builtin_amdgcn_mfma_f32_16x16x32_bf16(afrag[1][kk], b, acc[1][ct], 0, 0, 0);
        }
    }

#pragma unroll
    for (int s = 0; s < 2; ++s) {
#pragma unroll
        for (int r = 0; r < 4; ++r) {
            const int row = rowBase + s * 16 + lg * 4 + r;
            if (row < n) {
                ushort* op = Out + (size_t)row * 128 + lr;
#pragma unroll
                for (int ct = 0; ct < 8; ++ct)
                    op[ct * 16] = f2bf(acc[s][ct][r]);
            }
        }
    }
}

// ---------------------------------------------------------------------------
// Aggregation over bf16 H, bf16 out.  Unroll 8 (8 idx -> 8 dis + 8 row
// gathers in flight), tail 4, tail 1.  16 lanes/node, 16 nodes/block.
// ---------------------------------------------------------------------------
__global__ __launch_bounds__(256) void aggregate_kernel(const ushort* __restrict__ H,
                                                        const float* __restrict__ dis,
                                                        const int* __restrict__ rbeg,
                                                        const int* __restrict__ rend,
                                                        const int* __restrict__ csr,
                                                        const float* __restrict__ bias,
                                                        ushort* __restrict__ Out, int n) {
    const int g = threadIdx.x >> 4;
    const int l = threadIdx.x & 15;
    const int node = blockIdx.x * 16 + g;
    if (node >= n) return;

    const float dn = dis[node];
    const uint4 hq = *(const uint4*)(H + (size_t)node * 128 + l * 8);
    const int e0 = rbeg[node];
    const int e1 = rend[node];

    float s0_ = 0.f, s1_ = 0.f, s2_ = 0.f, s3_ = 0.f,
          s4_ = 0.f, s5_ = 0.f, s6_ = 0.f, s7_ = 0.f;

    int e = e0;
    for (; e + 8 <= e1; e += 8) {
        int a[8];
#pragma unroll
        for (int j = 0; j < 8; ++j) a[j] = csr[e + j];
        float w[8];
#pragma unroll
        for (int j = 0; j < 8; ++j) w[j] = dis[a[j]];
        uint4 h[8];
#pragma unroll
        for (int j = 0; j < 8; ++j) h[j] = *(const uint4*)(H + (size_t)a[j] * 128 + l * 8);
#pragma unroll
        for (int j = 0; j < 8; ++j) {
            s0_ += bf_lo(h[j].x) * w[j]; s1_ += bf_hi(h[j].x) * w[j];
            s2_ += bf_lo(h[j].y) * w[j]; s3_ += bf_hi(h[j].y) * w[j];
            s4_ += bf_lo(h[j].z) * w[j]; s5_ += bf_hi(h[j].z) * w[j];
            s6_ += bf_lo(h[j].w) * w[j]; s7_ += bf_hi(h[j].w) * w[j];
        }
    }
    for (; e + 4 <= e1; e += 4) {
        int a[4];
#pragma unroll
        for (int j = 0; j < 4; ++j) a[j] = csr[e + j];
        float w[4];
#pragma unroll
        for (int j = 0; j < 4; ++j) w[j] = dis[a[j]];
        uint4 h[4];
#pragma unroll
        for (int j = 0; j < 4; ++j) h[j] = *(const uint4*)(H + (size_t)a[j] * 128 + l * 8);
#pragma unroll
        for (int j = 0; j < 4; ++j) {
            s0_ += bf_lo(h[j].x) * w[j]; s1_ += bf_hi(h[j].x) * w[j];
            s2_ += bf_lo(h[j].y) * w[j]; s3_ += bf_hi(h[j].y) * w[j];
            s4_ += bf_lo(h[j].z) * w[j]; s5_ += bf_hi(h[j].z) * w[j];
            s6_ += bf_lo(h[j].w) * w[j]; s7_ += bf_hi(h[j].w) * w[j];
        }
    }
    for (; e < e1; ++e) {
        const int a = csr[e];
        const float w = dis[a];
        const uint4 h = *(const uint4*)(H + (size_t)a * 128 + l * 8);
        s0_ += bf_lo(h.x)*w; s1_ += bf_hi(h.x)*w;
        s2_ += bf_lo(h.y)*w; s3_ += bf_hi(h.y)*w;
        s4_ += bf_lo(h.z)*w; s5_ += bf_hi(h.z)*w;
        s6_ += bf_lo(h.w)*w; s7_ += bf_hi(h.w)*w;
    }

    const float self = dn * dn;
    const float4 bA = *(const float4*)&bias[l * 8];
    const float4 bB = *(const float4*)&bias[l * 8 + 4];
    float o0 = fmaxf(s0_ * dn + bf_lo(hq.x) * self + bA.x, 0.0f);
    float o1 = fmaxf(s1_ * dn + bf_hi(hq.x) * self + bA.y, 0.0f);
    float o2 = fmaxf(s2_ * dn + bf_lo(hq.y) * self + bA.z, 0.0f);
    float o3 = fmaxf(s3_ * dn + bf_hi(hq.y) * self + bA.w, 0.0f);
    float o4 = fmaxf(s4_ * dn + bf_lo(hq.z) * self + bB.x, 0.0f);
    float o5 = fmaxf(s5_ * dn + bf_hi(hq.z) * self + bB.y, 0.0f);
    float o6 = fmaxf(s6_ * dn + bf_lo(hq.w) * self + bB.z, 0.0f);
    float o7 = fmaxf(s7_ * dn + bf_hi(hq.w) * self + bB.w, 0.0f);

    uint4 o;
    o.x = pack2bf(o0, o1); o.y = pack2bf(o2, o3);
    o.z = pack2bf(o4, o5); o.w = pack2bf(o6, o7);
    *(uint4*)(Out + (size_t)node * 128 + l * 8) = o;
}

// ---------------------------------------------------------------------------
// Pool stage 1: segmented column-sum over bf16 X3.
// ---------------------------------------------------------------------------
__global__ __launch_bounds__(256) void pool_partial(const ushort* __restrict__ X,
                                                    const int* __restrict__ batch,
                                                    float* __restrict__ pooled,
                                                    int* __restrict__ gcnt, int n) {
    const int grp = threadIdx.x >> 7;
    const int t   = threadIdx.x & 127;
    const int r0  = blockIdx.x * 128 + grp * 64;
    if (r0 >= n) return;
    const int r1 = min(r0 + 64, n);

    int gcur = batch[r0];
    float sum = 0.0f;
    int cnt = 0;
    for (int r = r0; r < r1; ++r) {
        const int g = batch[r];
        const float v = bf1(X[(size_t)r * 128 + t]);
        if (g != gcur) {
            atomicAdd(&pooled[(size_t)gcur * 128 + t], sum);
            if (t == 0) atomicAdd(&gcnt[gcur], cnt);
            sum = 0.0f; cnt = 0; gcur = g;
        }
        sum += v; ++cnt;
    }
    atomicAdd(&pooled[(size_t)gcur * 128 + t], sum);
    if (t == 0) atomicAdd(&gcnt[gcur], cnt);
}

// ---------------------------------------------------------------------------
// Pool stage 2: divide by count + 128x10 linear.
// ---------------------------------------------------------------------------
__global__ __launch_bounds__(128) void pool_finalize(const float* __restrict__ pooled,
                                                     const int* __restrict__ gcnt,
                                                     const float* __restrict__ lw,
                                                     const float* __restrict__ lb,
                                                     float* __restrict__ out) {
    const int g = blockIdx.x;
    const int t = threadIdx.x;
    __shared__ float pl[128];
    const float c = fmaxf((float)gcnt[g], 1.0f);
    pl[t] = pooled[(size_t)g * 128 + t] / c;
    __syncthreads();
    if (t < 10) {
        float acc = lb[t];
#pragma unroll 16
        for (int d = 0; d < 128; ++d) acc += pl[d] * lw[d * 10 + t];
        out[g * 10 + t] = acc;
    }
}

// ---------------------------------------------------------------------------
extern "C" void kernel_launch(void* const* d_in, const int* in_sizes, int n_in,
                              void* d_out, int out_size, void* d_ws, size_t ws_size,
                              hipStream_t stream) {
    const int*   tokens = (const int*)d_in[0];
    const int*   eidx   = (const int*)d_in[1];
    const int*   batch  = (const int*)d_in[2];
    const float* emb    = (const float*)d_in[3];
    const float* w1     = (const float*)d_in[4];
    const float* b1     = (const float*)d_in[5];
    const float* w2     = (const float*)d_in[6];
    const float* b2     = (const float*)d_in[7];
    const float* lw     = (const float*)d_in[8];
    const float* lbv    = (const float*)d_in[9];

    const int N = in_sizes[0];
    const int E = in_sizes[1] / 2;
    const int G = out_size / 10;
    const int* src = eidx;
    const int* dst = eidx + E;
    const int NB = (N + 255) >> 8;

    char* p = (char*)d_ws;
    auto alloc = [&](size_t bytes) { void* r = (void*)p; p += (bytes + 255) & ~(size_t)255; return r; };
    float*  dis    = (float*)alloc((size_t)N * 4);
    int*    rbeg   = (int*)  alloc((size_t)N * 4);
    int*    rend   = (int*)  alloc((size_t)N * 4);
    // zeroed-per-call: bcur(256) | gcnt(512) | pooled(G*128 f32)
    int*    zreg   = (int*)  alloc((size_t)(768 + (size_t)G * 128) * 4);
    int*    bcur   = zreg;
    int*    gcnt   = zreg + 256;
    float*  pooled = (float*)(zreg + 768);
    uint*   bstage = (uint*) alloc((size_t)NB * CAP * 4);
    int*    csr    = (int*)  alloc((size_t)NB * CAP * 4);
    ushort* W1t    = (ushort*)alloc(16384 * 2);
    ushort* W2t    = (ushort*)alloc(16384 * 2);
    ushort* A      = (ushort*)alloc((size_t)N * 128 * 2);   // H / H2 (bf16)
    ushort* B      = (ushort*)alloc((size_t)N * 128 * 2);   // X2 / X3 (bf16)

    const int ZN4 = (768 + G * 128) / 4;
    const int EB  = (E + EPB - 1) / EPB;

    init_kernel   <<<(ZN4 + 255) / 256, 256, 0, stream>>>((int4*)zreg, ZN4);
    convert_w     <<<128, 256, 0, stream>>>(w1, w2, W1t, W2t);
    bucket_scatter<<<EB, 256, 0, stream>>>(src, dst, bcur, bstage, E, NB);
    csr_build     <<<NB, 256, 0, stream>>>(bstage, bcur, dis, rbeg, rend, csr, N, NB);

    // layer 1: H = bf16(emb[tokens]) @ W1 ; X2 = relu(agg(H)+b1) (bf16)
    gemm_mfma<true><<<(N + 127) / 128, 256, 0, stream>>>(nullptr, tokens, emb, W1t, A, N);
    aggregate_kernel<<<(N + 15) / 16, 256, 0, stream>>>(A, dis, rbeg, rend, csr, b1, B, N);

    // layer 2: H2 = X2 @ W2 ; X3 = relu(agg(H2)+b2) (bf16, overwrites B... -> A consumed)
    gemm_mfma<false><<<(N + 127) / 128, 256, 0, stream>>>(B, nullptr, nullptr, W2t, A, N);
    aggregate_kernel<<<(N + 15) / 16, 256, 0, stream>>>(A, dis, rbeg, rend, csr, b2, B, N);

    // mean pool + classifier
    pool_partial <<<(N + 127) / 128, 256, 0, stream>>>(B, batch, pooled, gcnt, N);
    pool_finalize<<<G, 128, 0, stream>>>(pooled, gcnt, lw, lbv, (float*)d_out);
}

// Round 10
// 142.605 us; speedup vs baseline: 1.1720x; 1.0873x over previous
//
#include <hip/hip_runtime.h>
#include <hip/hip_bf16.h>

// ---------------------------------------------------------------------------
// GCN classifier.  R1: multi-block scan.  R2: agg unroll.  R3: bf16
// activations.  R4: bucketed counting-sort CSR.  R5: 2-stage pool + init
// kernel.  R6: MFMA GEMM.  R9: fixed-capacity buckets, agg unroll 8.
// R10: (a) GEMM epilogue pre-scales rows by dis -> aggregate is a pure
//      gather-sum (no dis[src] gather, no per-term multiply);
//      (b) mean-pool fused into agg2 via LDS [16][128] staging + sorted-run
//      atomic flush (X3 buffer and pool_partial kernel deleted; finalize
//      binary-searches batch for counts);
//      (c) init+convert_w merged into one launch.  10 -> 8 kernels.
// ---------------------------------------------------------------------------

typedef unsigned int uint;
typedef unsigned short ushort;
typedef __attribute__((ext_vector_type(8))) short bf16x8;
typedef __attribute__((ext_vector_type(4))) float f32x4;

__device__ inline float bf_lo(uint u) { return __uint_as_float(u << 16); }
__device__ inline float bf_hi(uint u) { return __uint_as_float(u & 0xffff0000u); }
__device__ inline ushort f2bf(float f) {           // round-to-nearest-even
    uint u = __float_as_uint(f);
    return (ushort)((u + 0x7fffu + ((u >> 16) & 1u)) >> 16);
}
__device__ inline uint pack2bf(float a, float b) {
    return (uint)f2bf(a) | ((uint)f2bf(b) << 16);
}

#define EPB 2048   // edges per block in bucketing kernels
#define CAP 8192   // per-bucket staged-edge capacity (avg 4082, Poisson tail ~0)

// ---- 0) zero accumulators (bcur|pooled) + convert both weight matrices ----
__global__ __launch_bounds__(256) void init_convert(int4* __restrict__ z, int n4,
                                                    const float* __restrict__ W1,
                                                    const float* __restrict__ W2,
                                                    ushort* __restrict__ W1t,
                                                    ushort* __restrict__ W2t) {
    const int zb = (n4 + 255) >> 8;
    if ((int)blockIdx.x < zb) {
        int i = blockIdx.x * 256 + threadIdx.x;
        if (i < n4) z[i] = make_int4(0, 0, 0, 0);
    } else {
        int i = (blockIdx.x - zb) * 256 + threadIdx.x;   // 0..32767
        const float* Ws = (i < 16384) ? W1 : W2;
        ushort* Wd      = (i < 16384) ? W1t : W2t;
        int j = i & 16383;
        int nn = j >> 7, k = j & 127;
        Wd[j] = f2bf(Ws[k * 128 + nn]);
    }
}

// ---- 1) scatter edges into fixed-capacity bucket regions (LDS presort) ----
__global__ __launch_bounds__(256) void bucket_scatter(const int* __restrict__ src,
                                                      const int* __restrict__ dst,
                                                      int* __restrict__ bcur,
                                                      uint* __restrict__ bstage,
                                                      int E, int NB) {
    __shared__ int lh[256];
    __shared__ int lbase[257];
    __shared__ int gbase[256];
    __shared__ int lcur[256];
    __shared__ uint stage[EPB];
    const int t = threadIdx.x;
    const int base = blockIdx.x * EPB;
    const int end  = min(E, base + EPB);
    const int tot  = end - base;

    lh[t] = 0;
    __syncthreads();

    uint pk[8]; int bk[8]; int cnt = 0;
    for (int i = base + t; i < end; i += 256) {
        int s = src[i];
        uint d = (uint)dst[i];
        bk[cnt] = (int)(d >> 8);
        pk[cnt] = (uint)s | ((d & 255u) << 24);
        atomicAdd(&lh[bk[cnt]], 1);
        ++cnt;
    }
    __syncthreads();

    if (t < NB && lh[t]) gbase[t] = t * CAP + atomicAdd(&bcur[t], lh[t]);
    {
        __shared__ int ls[256];
        int v = lh[t];
        ls[t] = v;
        __syncthreads();
        for (int off = 1; off < 256; off <<= 1) {
            int x = (t >= off) ? ls[t - off] : 0;
            __syncthreads();
            ls[t] += x;
            __syncthreads();
        }
        lbase[t] = ls[t] - v;
        if (t == 255) lbase[256] = ls[255];
        lcur[t] = 0;
    }
    __syncthreads();

    for (int j = 0; j < cnt; ++j) {
        int p = lbase[bk[j]] + atomicAdd(&lcur[bk[j]], 1);
        stage[p] = pk[j];
    }
    __syncthreads();

    for (int i = t; i < tot; i += 256) {
        int lo = 0, hi = 256;
        while (lo + 1 < hi) {
            int mid = (lo + hi) >> 1;
            if (lbase[mid] <= i) lo = mid; else hi = mid;
        }
        bstage[gbase[lo] + (i - lbase[lo])] = stage[i];
    }
}

// ---- 2) per-bucket: node hist -> dis + rbeg/rend (coalesced), then CSR ----
__global__ __launch_bounds__(256) void csr_build(const uint* __restrict__ bstage,
                                                 const int* __restrict__ bcur,
                                                 float* __restrict__ dis,
                                                 int* __restrict__ rbeg,
                                                 int* __restrict__ rend,
                                                 int* __restrict__ csr,
                                                 int N, int NB) {
    __shared__ int lh[256];
    __shared__ int ls[256];
    __shared__ int lbase[256];
    __shared__ int lcur[256];
    const int b = blockIdx.x;
    const int t = threadIdx.x;
    const int base  = b * CAP;
    const int cntb  = bcur[b];
    const int n0    = b << 8;
    const int nn    = min(256, N - n0);

    lh[t] = 0;
    __syncthreads();
    for (int i = t; i < cntb; i += 256)
        atomicAdd(&lh[bstage[base + i] >> 24], 1);
    __syncthreads();

    const int v = lh[t];
    ls[t] = v;
    __syncthreads();
    for (int off = 1; off < 256; off <<= 1) {
        int x = (t >= off) ? ls[t - off] : 0;
        __syncthreads();
        ls[t] += x;
        __syncthreads();
    }
    lbase[t] = ls[t] - v;
    lcur[t] = 0;
    if (t < nn) {
        dis[n0 + t]  = rsqrtf((float)v + 1.0f);
        rbeg[n0 + t] = base + lbase[t];
        rend[n0 + t] = base + lbase[t] + v;
    }
    __syncthreads();

    for (int i = t; i < cntb; i += 256) {
        uint e = bstage[base + i];
        int dl = (int)(e >> 24);
        int pos = base + lbase[dl] + atomicAdd(&lcur[dl], 1);
        csr[pos] = (int)(e & 0xFFFFFFu);
    }
}

// ---------------------------------------------------------------------------
// MFMA GEMM: Out_bf16[n,128] = (A[n,128] @ W[128,128]) * dis[row]
// Wt: bf16, pre-transposed [n(out col)][k].  Block = 4 waves, 128 rows.
// ---------------------------------------------------------------------------
template<bool GATHER>
__global__ __launch_bounds__(256) void gemm_mfma(const ushort* __restrict__ Xbf,
                                                 const int* __restrict__ tokens,
                                                 const float* __restrict__ emb,
                                                 const ushort* __restrict__ Wt,
                                                 const float* __restrict__ dis,
                                                 ushort* __restrict__ Out, int n) {
    __shared__ ushort wl[128 * 128];   // 32KB, swizzled
    const int tid = threadIdx.x;

    {
        const int row  = tid >> 1;
        const int half = tid & 1;
        const int base = row * 256 + half * 128;
#pragma unroll
        for (int i = 0; i < 8; ++i) {
            int off = base + i * 16;
            uint4 v = *(const uint4*)((const char*)Wt + off);
            int swz = off ^ ((row & 7) << 4);
            *(uint4*)((char*)wl + swz) = v;
        }
    }
    __syncthreads();

    const int w  = tid >> 6;
    const int l  = tid & 63;
    const int lr = l & 15;
    const int lg = l >> 4;
    const int rowBase = blockIdx.x * 128 + w * 32;

    f32x4 acc[2][8];
#pragma unroll
    for (int s = 0; s < 2; ++s)
#pragma unroll
        for (int ct = 0; ct < 8; ++ct) acc[s][ct] = (f32x4){0.f, 0.f, 0.f, 0.f};

    bf16x8 afrag[2][4];
#pragma unroll
    for (int s = 0; s < 2; ++s) {
        const int row = rowBase + s * 16 + lr;
        if (row < n) {
            if (GATHER) {
                const int tok = tokens[row];
                if (tok != 0) {
                    const float* ep = emb + (size_t)tok * 128;
#pragma unroll
                    for (int kk = 0; kk < 4; ++kk) {
                        const float* q = ep + kk * 32 + lg * 8;
                        float4 lo = *(const float4*)q;
                        float4 hi = *(const float4*)(q + 4);
                        uint4 pk;
                        pk.x = pack2bf(lo.x, lo.y); pk.y = pack2bf(lo.z, lo.w);
                        pk.z = pack2bf(hi.x, hi.y); pk.w = pack2bf(hi.z, hi.w);
                        union { uint4 u; bf16x8 b; } c; c.u = pk;
                        afrag[s][kk] = c.b;
                    }
                } else {
#pragma unroll
                    for (int kk = 0; kk < 4; ++kk) afrag[s][kk] = (bf16x8){0,0,0,0,0,0,0,0};
                }
            } else {
                const ushort* xp = Xbf + (size_t)row * 128;
#pragma unroll
                for (int kk = 0; kk < 4; ++kk)
                    afrag[s][kk] = *(const bf16x8*)(xp + kk * 32 + lg * 8);
            }
        } else {
#pragma unroll
            for (int kk = 0; kk < 4; ++kk) afrag[s][kk] = (bf16x8){0,0,0,0,0,0,0,0};
        }
    }

#pragma unroll
    for (int ct = 0; ct < 8; ++ct) {
#pragma unroll
        for (int kk = 0; kk < 4; ++kk) {
            const int nrow = ct * 16 + lr;
            int off = nrow * 256 + kk * 64 + lg * 16;
            off ^= ((nrow & 7) << 4);
            bf16x8 b = *(const bf16x8*)((const char*)wl + off);
            acc[0][ct] = __builtin_amdgcn_mfma_f32_16x16x32_bf16(afrag[0][kk], b, acc[0][ct], 0, 0, 0);
            acc[1][ct] = __builtin_amdgcn_mfma_f32_16x16x32_bf16(afrag[1][kk], b, acc[1][ct], 0, 0, 0);
        }
    }

    // store Hs = acc * dis[row]  (pre-scaled for the aggregate)
#pragma unroll
    for (int s = 0; s < 2; ++s) {
#pragma unroll
        for (int r = 0; r < 4; ++r) {
            const int row = rowBase + s * 16 + lg * 4 + r;
            if (row < n) {
                const float sc = dis[row];
                ushort* op = Out + (size_t)row * 128 + lr;
#pragma unroll
                for (int ct = 0; ct < 8; ++ct)
                    op[ct * 16] = f2bf(acc[s][ct][r] * sc);
            }
        }
    }
}

// ---------------------------------------------------------------------------
// Aggregation over pre-scaled Hs:  o = relu( dn*(sum_e Hs[src] + Hs[node]) + b )
// Pure gather-sum (no dis gather, no multiplies in the loop).  16 lanes/node.
// FUSE_POOL: instead of writing X3, stage rows in LDS and flush per-graph
// partial sums (batch sorted) to pooled via atomics.
// ---------------------------------------------------------------------------
template<bool FUSE_POOL>
__global__ __launch_bounds__(256) void aggregate_kernel(const ushort* __restrict__ H,
                                                        const float* __restrict__ dis,
                                                        const int* __restrict__ rbeg,
                                                        const int* __restrict__ rend,
                                                        const int* __restrict__ csr,
                                                        const float* __restrict__ bias,
                                                        ushort* __restrict__ Out,
                                                        const int* __restrict__ batch,
                                                        float* __restrict__ pooled,
                                                        int n) {
    const int g = threadIdx.x >> 4;
    const int l = threadIdx.x & 15;
    const int node = blockIdx.x * 16 + g;
    const bool valid = node < n;

    float s0_=0.f,s1_=0.f,s2_=0.f,s3_=0.f,s4_=0.f,s5_=0.f,s6_=0.f,s7_=0.f;
    float dn = 0.f;
    const float4 bA = *(const float4*)&bias[l * 8];
    const float4 bB = *(const float4*)&bias[l * 8 + 4];

    if (valid) {
        dn = dis[node];
        const uint4 hq = *(const uint4*)(H + (size_t)node * 128 + l * 8);
        s0_ = bf_lo(hq.x); s1_ = bf_hi(hq.x);
        s2_ = bf_lo(hq.y); s3_ = bf_hi(hq.y);
        s4_ = bf_lo(hq.z); s5_ = bf_hi(hq.z);
        s6_ = bf_lo(hq.w); s7_ = bf_hi(hq.w);

        const int e0 = rbeg[node];
        const int e1 = rend[node];
        int e = e0;
        for (; e + 8 <= e1; e += 8) {
            int a[8];
#pragma unroll
            for (int j = 0; j < 8; ++j) a[j] = csr[e + j];
            uint4 h[8];
#pragma unroll
            for (int j = 0; j < 8; ++j) h[j] = *(const uint4*)(H + (size_t)a[j] * 128 + l * 8);
#pragma unroll
            for (int j = 0; j < 8; ++j) {
                s0_ += bf_lo(h[j].x); s1_ += bf_hi(h[j].x);
                s2_ += bf_lo(h[j].y); s3_ += bf_hi(h[j].y);
                s4_ += bf_lo(h[j].z); s5_ += bf_hi(h[j].z);
                s6_ += bf_lo(h[j].w); s7_ += bf_hi(h[j].w);
            }
        }
        for (; e + 4 <= e1; e += 4) {
            int a[4];
#pragma unroll
            for (int j = 0; j < 4; ++j) a[j] = csr[e + j];
            uint4 h[4];
#pragma unroll
            for (int j = 0; j < 4; ++j) h[j] = *(const uint4*)(H + (size_t)a[j] * 128 + l * 8);
#pragma unroll
            for (int j = 0; j < 4; ++j) {
                s0_ += bf_lo(h[j].x); s1_ += bf_hi(h[j].x);
                s2_ += bf_lo(h[j].y); s3_ += bf_hi(h[j].y);
                s4_ += bf_lo(h[j].z); s5_ += bf_hi(h[j].z);
                s6_ += bf_lo(h[j].w); s7_ += bf_hi(h[j].w);
            }
        }
        for (; e < e1; ++e) {
            const uint4 h = *(const uint4*)(H + (size_t)csr[e] * 128 + l * 8);
            s0_ += bf_lo(h.x); s1_ += bf_hi(h.x);
            s2_ += bf_lo(h.y); s3_ += bf_hi(h.y);
            s4_ += bf_lo(h.z); s5_ += bf_hi(h.z);
            s6_ += bf_lo(h.w); s7_ += bf_hi(h.w);
        }
    }

    const float o0 = fmaxf(s0_ * dn + bA.x, 0.0f);
    const float o1 = fmaxf(s1_ * dn + bA.y, 0.0f);
    const float o2 = fmaxf(s2_ * dn + bA.z, 0.0f);
    const float o3 = fmaxf(s3_ * dn + bA.w, 0.0f);
    const float o4 = fmaxf(s4_ * dn + bB.x, 0.0f);
    const float o5 = fmaxf(s5_ * dn + bB.y, 0.0f);
    const float o6 = fmaxf(s6_ * dn + bB.z, 0.0f);
    const float o7 = fmaxf(s7_ * dn + bB.w, 0.0f);

    if constexpr (!FUSE_POOL) {
        if (valid) {
            uint4 o;
            o.x = pack2bf(o0, o1); o.y = pack2bf(o2, o3);
            o.z = pack2bf(o4, o5); o.w = pack2bf(o6, o7);
            *(uint4*)(Out + (size_t)node * 128 + l * 8) = o;
        }
    } else {
        __shared__ float x3[16][128];
        __shared__ int bv[16];
        if (valid) {
            float4 va, vb;
            va.x = o0; va.y = o1; va.z = o2; va.w = o3;
            vb.x = o4; vb.y = o5; vb.z = o6; vb.w = o7;
            *(float4*)&x3[g][l * 8]     = va;
            *(float4*)&x3[g][l * 8 + 4] = vb;
            if (l == 0) bv[g] = batch[node];
        } else if (l == 0) {
            bv[g] = -1;
        }
        __syncthreads();
        const int t = threadIdx.x;
        if (t < 128) {
            int cur = bv[0];
            float run = 0.0f;
            for (int r = 0; r < 16; ++r) {
                const int b = bv[r];
                if (b < 0) break;                       // tail (batch sorted)
                if (b != cur) {
                    if (run != 0.0f) atomicAdd(&pooled[(size_t)cur * 128 + t], run);
                    cur = b; run = 0.0f;
                }
                run += x3[r][t];
            }
            if (cur >= 0 && run != 0.0f) atomicAdd(&pooled[(size_t)cur * 128 + t], run);
        }
    }
}

// ---------------------------------------------------------------------------
// Pool finalize: counts via binary search on sorted batch, divide, 128x10.
// ---------------------------------------------------------------------------
__global__ __launch_bounds__(128) void pool_finalize(const float* __restrict__ pooled,
                                                     const int* __restrict__ batch,
                                                     const float* __restrict__ lw,
                                                     const float* __restrict__ lb,
                                                     float* __restrict__ out, int n) {
    const int g = blockIdx.x;
    const int t = threadIdx.x;
    int lo = 0, hi = n;
    while (lo < hi) { int mid = (lo + hi) >> 1; if (batch[mid] < g) lo = mid + 1; else hi = mid; }
    const int s = lo;
    hi = n;
    while (lo < hi) { int mid = (lo + hi) >> 1; if (batch[mid] < g + 1) lo = mid + 1; else hi = mid; }
    const float c = fmaxf((float)(lo - s), 1.0f);

    __shared__ float pl[128];
    pl[t] = pooled[(size_t)g * 128 + t] / c;
    __syncthreads();
    if (t < 10) {
        float acc = lb[t];
#pragma unroll 16
        for (int d = 0; d < 128; ++d) acc += pl[d] * lw[d * 10 + t];
        out[g * 10 + t] = acc;
    }
}

// ---------------------------------------------------------------------------
extern "C" void kernel_launch(void* const* d_in, const int* in_sizes, int n_in,
                              void* d_out, int out_size, void* d_ws, size_t ws_size,
                              hipStream_t stream) {
    const int*   tokens = (const int*)d_in[0];
    const int*   eidx   = (const int*)d_in[1];
    const int*   batch  = (const int*)d_in[2];
    const float* emb    = (const float*)d_in[3];
    const float* w1     = (const float*)d_in[4];
    const float* b1     = (const float*)d_in[5];
    const float* w2     = (const float*)d_in[6];
    const float* b2     = (const float*)d_in[7];
    const float* lw     = (const float*)d_in[8];
    const float* lbv    = (const float*)d_in[9];

    const int N = in_sizes[0];
    const int E = in_sizes[1] / 2;
    const int G = out_size / 10;
    const int* src = eidx;
    const int* dst = eidx + E;
    const int NB = (N + 255) >> 8;

    char* p = (char*)d_ws;
    auto alloc = [&](size_t bytes) { void* r = (void*)p; p += (bytes + 255) & ~(size_t)255; return r; };
    float*  dis    = (float*)alloc((size_t)N * 4);
    int*    rbeg   = (int*)  alloc((size_t)N * 4);
    int*    rend   = (int*)  alloc((size_t)N * 4);
    // zeroed-per-call: bcur(256) | pooled(G*128 f32)
    int*    zreg   = (int*)  alloc((size_t)(256 + (size_t)G * 128) * 4);
    int*    bcur   = zreg;
    float*  pooled = (float*)(zreg + 256);
    uint*   bstage = (uint*) alloc((size_t)NB * CAP * 4);
    int*    csr    = (int*)  alloc((size_t)NB * CAP * 4);
    ushort* W1t    = (ushort*)alloc(16384 * 2);
    ushort* W2t    = (ushort*)alloc(16384 * 2);
    ushort* A      = (ushort*)alloc((size_t)N * 128 * 2);   // Hs1 / Hs2 (bf16)
    ushort* B      = (ushort*)alloc((size_t)N * 128 * 2);   // X2 (bf16)

    const int ZN4 = (256 + G * 128) / 4;
    const int ZB  = (ZN4 + 255) / 256;
    const int EB  = (E + EPB - 1) / EPB;

    init_convert  <<<ZB + 128, 256, 0, stream>>>((int4*)zreg, ZN4, w1, w2, W1t, W2t);
    bucket_scatter<<<EB, 256, 0, stream>>>(src, dst, bcur, bstage, E, NB);
    csr_build     <<<NB, 256, 0, stream>>>(bstage, bcur, dis, rbeg, rend, csr, N, NB);

    // layer 1: Hs1 = (bf16(emb[tokens]) @ W1) * dis ; X2 = relu(dn*(sum+self)+b1)
    gemm_mfma<true><<<(N + 127) / 128, 256, 0, stream>>>(nullptr, tokens, emb, W1t, dis, A, N);
    aggregate_kernel<false><<<(N + 15) / 16, 256, 0, stream>>>(A, dis, rbeg, rend, csr, b1, B, nullptr, nullptr, N);

    // layer 2: Hs2 = (X2 @ W2) * dis ; agg2 fused with mean-pool partials
    gemm_mfma<false><<<(N + 127) / 128, 256, 0, stream>>>(B, nullptr, nullptr, W2t, dis, A, N);
    aggregate_kernel<true><<<(N + 15) / 16, 256, 0, stream>>>(A, dis, rbeg, rend, csr, b2, nullptr, batch, pooled, N);

    // finalize: counts by binary search + 128x10 linear
    pool_finalize<<<G, 128, 0, stream>>>(pooled, batch, lw, lbv, (float*)d_out, N);
}

// Round 11
// 136.967 us; speedup vs baseline: 1.2203x; 1.0412x over previous
//
#include <hip/hip_runtime.h>
#include <hip/hip_bf16.h>

// ---------------------------------------------------------------------------
// GCN classifier.  R1: multi-block scan.  R2: agg unroll.  R3: bf16
// activations.  R4: bucketed counting-sort CSR.  R5: 2-stage pool.
// R6: MFMA GEMM.  R9: fixed-capacity buckets, agg unroll 8.  R10: pre-scaled
// rows + pool fused into agg2.
// R11: critical-path surgery. gemm1 decoupled from CSR chain (layer-1 H is
//      UNSCALED; agg1 gathers dis[src] like R9) so csr_build can run IN THE
//      SAME LAUNCH as gemm1 (grid-split, csr blocks first, LDS aliased).
//      pooled zeroing also moved into that launch. init shrinks to bcur+W
//      convert. Layer 2 keeps pre-scale (dis ready) + fused pool.
//      8 launches -> 7; csr_build (~8us) hidden under gemm1.
// ---------------------------------------------------------------------------

typedef unsigned int uint;
typedef unsigned short ushort;
typedef __attribute__((ext_vector_type(8))) short bf16x8;
typedef __attribute__((ext_vector_type(4))) float f32x4;

__device__ inline float bf_lo(uint u) { return __uint_as_float(u << 16); }
__device__ inline float bf_hi(uint u) { return __uint_as_float(u & 0xffff0000u); }
__device__ inline ushort f2bf(float f) {           // round-to-nearest-even
    uint u = __float_as_uint(f);
    return (ushort)((u + 0x7fffu + ((u >> 16) & 1u)) >> 16);
}
__device__ inline uint pack2bf(float a, float b) {
    return (uint)f2bf(a) | ((uint)f2bf(b) << 16);
}

#define EPB 2048   // edges per block in bucketing kernels
#define CAP 8192   // per-bucket staged-edge capacity (avg 4082, Poisson tail ~0)

// ---- 0) zero bcur (block 0) + convert both weights (blocks 1..128) --------
__global__ __launch_bounds__(256) void init0(int* __restrict__ bcur,
                                             const float* __restrict__ W1,
                                             const float* __restrict__ W2,
                                             ushort* __restrict__ W1t,
                                             ushort* __restrict__ W2t) {
    if (blockIdx.x == 0) {
        bcur[threadIdx.x] = 0;
    } else {
        int i = (blockIdx.x - 1) * 256 + threadIdx.x;    // 0..32767
        const float* Ws = (i < 16384) ? W1 : W2;
        ushort* Wd      = (i < 16384) ? W1t : W2t;
        int j = i & 16383;
        int nn = j >> 7, k = j & 127;
        Wd[j] = f2bf(Ws[k * 128 + nn]);
    }
}

// ---- 1) scatter edges into fixed-capacity bucket regions (LDS presort) ----
__global__ __launch_bounds__(256) void bucket_scatter(const int* __restrict__ src,
                                                      const int* __restrict__ dst,
                                                      int* __restrict__ bcur,
                                                      uint* __restrict__ bstage,
                                                      int E, int NB) {
    __shared__ int lh[256];
    __shared__ int lbase[257];
    __shared__ int gbase[256];
    __shared__ int lcur[256];
    __shared__ uint stage[EPB];
    const int t = threadIdx.x;
    const int base = blockIdx.x * EPB;
    const int end  = min(E, base + EPB);
    const int tot  = end - base;

    lh[t] = 0;
    __syncthreads();

    uint pk[8]; int bk[8]; int cnt = 0;
    for (int i = base + t; i < end; i += 256) {
        int s = src[i];
        uint d = (uint)dst[i];
        bk[cnt] = (int)(d >> 8);
        pk[cnt] = (uint)s | ((d & 255u) << 24);
        atomicAdd(&lh[bk[cnt]], 1);
        ++cnt;
    }
    __syncthreads();

    if (t < NB && lh[t]) gbase[t] = t * CAP + atomicAdd(&bcur[t], lh[t]);
    {
        __shared__ int ls[256];
        int v = lh[t];
        ls[t] = v;
        __syncthreads();
        for (int off = 1; off < 256; off <<= 1) {
            int x = (t >= off) ? ls[t - off] : 0;
            __syncthreads();
            ls[t] += x;
            __syncthreads();
        }
        lbase[t] = ls[t] - v;
        if (t == 255) lbase[256] = ls[255];
        lcur[t] = 0;
    }
    __syncthreads();

    for (int j = 0; j < cnt; ++j) {
        int p = lbase[bk[j]] + atomicAdd(&lcur[bk[j]], 1);
        stage[p] = pk[j];
    }
    __syncthreads();

    for (int i = t; i < tot; i += 256) {
        int lo = 0, hi = 256;
        while (lo + 1 < hi) {
            int mid = (lo + hi) >> 1;
            if (lbase[mid] <= i) lo = mid; else hi = mid;
        }
        bstage[gbase[lo] + (i - lbase[lo])] = stage[i];
    }
}

// ---- csr_build body (uses caller-provided 4KB of LDS) ---------------------
__device__ void csr_body(int* lds,                       // >= 1024 ints
                         const uint* __restrict__ bstage,
                         const int* __restrict__ bcur,
                         float* __restrict__ dis,
                         int* __restrict__ rbeg,
                         int* __restrict__ rend,
                         int* __restrict__ csr,
                         int N, int b) {
    int* lh    = lds;
    int* ls    = lds + 256;
    int* lbase = lds + 512;
    int* lcur  = lds + 768;
    const int t = threadIdx.x;
    const int base  = b * CAP;
    const int cntb  = bcur[b];
    const int n0    = b << 8;
    const int nn    = min(256, N - n0);

    lh[t] = 0;
    __syncthreads();
    for (int i = t; i < cntb; i += 256)
        atomicAdd(&lh[bstage[base + i] >> 24], 1);
    __syncthreads();

    const int v = lh[t];
    ls[t] = v;
    __syncthreads();
    for (int off = 1; off < 256; off <<= 1) {
        int x = (t >= off) ? ls[t - off] : 0;
        __syncthreads();
        ls[t] += x;
        __syncthreads();
    }
    lbase[t] = ls[t] - v;
    lcur[t] = 0;
    if (t < nn) {
        dis[n0 + t]  = rsqrtf((float)v + 1.0f);
        rbeg[n0 + t] = base + lbase[t];
        rend[n0 + t] = base + lbase[t] + v;
    }
    __syncthreads();

    for (int i = t; i < cntb; i += 256) {
        uint e = bstage[base + i];
        int dl = (int)(e >> 24);
        int pos = base + lbase[dl] + atomicAdd(&lcur[dl], 1);
        csr[pos] = (int)(e & 0xFFFFFFu);
    }
}

// ---- MFMA GEMM body (uses caller-provided 32KB LDS) ------------------------
// Out_bf16[n,128] = (A[n,128] @ W[128,128]) * (SCALE ? dis[row] : 1)
template<bool GATHER, bool SCALE>
__device__ void gemm_body(ushort* wl,
                          const ushort* __restrict__ Xbf,
                          const int* __restrict__ tokens,
                          const float* __restrict__ emb,
                          const ushort* __restrict__ Wt,
                          const float* __restrict__ dis,
                          ushort* __restrict__ Out, int n, int bid) {
    const int tid = threadIdx.x;
    {
        const int row  = tid >> 1;
        const int half = tid & 1;
        const int base = row * 256 + half * 128;
#pragma unroll
        for (int i = 0; i < 8; ++i) {
            int off = base + i * 16;
            uint4 v = *(const uint4*)((const char*)Wt + off);
            int swz = off ^ ((row & 7) << 4);
            *(uint4*)((char*)wl + swz) = v;
        }
    }
    __syncthreads();

    const int w  = tid >> 6;
    const int l  = tid & 63;
    const int lr = l & 15;
    const int lg = l >> 4;
    const int rowBase = bid * 128 + w * 32;

    f32x4 acc[2][8];
#pragma unroll
    for (int s = 0; s < 2; ++s)
#pragma unroll
        for (int ct = 0; ct < 8; ++ct) acc[s][ct] = (f32x4){0.f, 0.f, 0.f, 0.f};

    bf16x8 afrag[2][4];
#pragma unroll
    for (int s = 0; s < 2; ++s) {
        const int row = rowBase + s * 16 + lr;
        if (row < n) {
            if (GATHER) {
                const int tok = tokens[row];
                if (tok != 0) {
                    const float* ep = emb + (size_t)tok * 128;
#pragma unroll
                    for (int kk = 0; kk < 4; ++kk) {
                        const float* q = ep + kk * 32 + lg * 8;
                        float4 lo = *(const float4*)q;
                        float4 hi = *(const float4*)(q + 4);
                        uint4 pk;
                        pk.x = pack2bf(lo.x, lo.y); pk.y = pack2bf(lo.z, lo.w);
                        pk.z = pack2bf(hi.x, hi.y); pk.w = pack2bf(hi.z, hi.w);
                        union { uint4 u; bf16x8 b; } c; c.u = pk;
                        afrag[s][kk] = c.b;
                    }
                } else {
#pragma unroll
                    for (int kk = 0; kk < 4; ++kk) afrag[s][kk] = (bf16x8){0,0,0,0,0,0,0,0};
                }
            } else {
                const ushort* xp = Xbf + (size_t)row * 128;
#pragma unroll
                for (int kk = 0; kk < 4; ++kk)
                    afrag[s][kk] = *(const bf16x8*)(xp + kk * 32 + lg * 8);
            }
        } else {
#pragma unroll
            for (int kk = 0; kk < 4; ++kk) afrag[s][kk] = (bf16x8){0,0,0,0,0,0,0,0};
        }
    }

#pragma unroll
    for (int ct = 0; ct < 8; ++ct) {
#pragma unroll
        for (int kk = 0; kk < 4; ++kk) {
            const int nrow = ct * 16 + lr;
            int off = nrow * 256 + kk * 64 + lg * 16;
            off ^= ((nrow & 7) << 4);
            bf16x8 b = *(const bf16x8*)((const char*)wl + off);
            acc[0][ct] = __builtin_amdgcn_mfma_f32_16x16x32_bf16(afrag[0][kk], b, acc[0][ct], 0, 0, 0);
            acc[1][ct] = __builtin_amdgcn_mfma_f32_16x16x32_bf16(afrag[1][kk], b, acc[1][ct], 0, 0, 0);
        }
    }

#pragma unroll
    for (int s = 0; s < 2; ++s) {
#pragma unroll
        for (int r = 0; r < 4; ++r) {
            const int row = rowBase + s * 16 + lg * 4 + r;
            if (row < n) {
                const float sc = SCALE ? dis[row] : 1.0f;
                ushort* op = Out + (size_t)row * 128 + lr;
#pragma unroll
                for (int ct = 0; ct < 8; ++ct)
                    op[ct * 16] = f2bf(acc[s][ct][r] * sc);
            }
        }
    }
}

// ---- 2) fused: csr_build | gemm1(unscaled, emb-gather) | pooled zero ------
__global__ __launch_bounds__(256) void csr_gemm1_fused(const uint* __restrict__ bstage,
                                                       const int* __restrict__ bcur,
                                                       float* __restrict__ dis,
                                                       int* __restrict__ rbeg,
                                                       int* __restrict__ rend,
                                                       int* __restrict__ csr,
                                                       const int* __restrict__ tokens,
                                                       const float* __restrict__ emb,
                                                       const ushort* __restrict__ W1t,
                                                       ushort* __restrict__ H,
                                                       int4* __restrict__ poolz, int pz4,
                                                       int N, int NB, int GB) {
    __shared__ ushort wl[128 * 128];   // 32KB; csr path aliases first 4KB
    const int b = blockIdx.x;
    if (b < NB) {
        csr_body((int*)wl, bstage, bcur, dis, rbeg, rend, csr, N, b);
    } else if (b < NB + GB) {
        gemm_body<true, false>(wl, nullptr, tokens, emb, W1t, nullptr, H, N, b - NB);
    } else {
        int i = (b - NB - GB) * 256 + threadIdx.x;
        if (i < pz4) poolz[i] = make_int4(0, 0, 0, 0);
    }
}

// ---- standalone gemm2 (pre-scaled) ----------------------------------------
__global__ __launch_bounds__(256) void gemm2_kernel(const ushort* __restrict__ Xbf,
                                                    const ushort* __restrict__ Wt,
                                                    const float* __restrict__ dis,
                                                    ushort* __restrict__ Out, int n) {
    __shared__ ushort wl[128 * 128];
    gemm_body<false, true>(wl, Xbf, nullptr, nullptr, Wt, dis, Out, n, blockIdx.x);
}

// ---------------------------------------------------------------------------
// agg1: H unscaled -> o = relu( dn*sum_e H[src]*dis[src] + H[node]*dn^2 + b )
// unroll 8 / 4 / 1; 16 lanes/node; bf16 out.
// ---------------------------------------------------------------------------
__global__ __launch_bounds__(256) void aggregate_w(const ushort* __restrict__ H,
                                                   const float* __restrict__ dis,
                                                   const int* __restrict__ rbeg,
                                                   const int* __restrict__ rend,
                                                   const int* __restrict__ csr,
                                                   const float* __restrict__ bias,
                                                   ushort* __restrict__ Out, int n) {
    const int g = threadIdx.x >> 4;
    const int l = threadIdx.x & 15;
    const int node = blockIdx.x * 16 + g;
    if (node >= n) return;

    const float dn = dis[node];
    const uint4 hq = *(const uint4*)(H + (size_t)node * 128 + l * 8);
    const int e0 = rbeg[node];
    const int e1 = rend[node];

    float s0_=0.f,s1_=0.f,s2_=0.f,s3_=0.f,s4_=0.f,s5_=0.f,s6_=0.f,s7_=0.f;

    int e = e0;
    for (; e + 8 <= e1; e += 8) {
        int a[8];
#pragma unroll
        for (int j = 0; j < 8; ++j) a[j] = csr[e + j];
        float w[8];
#pragma unroll
        for (int j = 0; j < 8; ++j) w[j] = dis[a[j]];
        uint4 h[8];
#pragma unroll
        for (int j = 0; j < 8; ++j) h[j] = *(const uint4*)(H + (size_t)a[j] * 128 + l * 8);
#pragma unroll
        for (int j = 0; j < 8; ++j) {
            s0_ += bf_lo(h[j].x) * w[j]; s1_ += bf_hi(h[j].x) * w[j];
            s2_ += bf_lo(h[j].y) * w[j]; s3_ += bf_hi(h[j].y) * w[j];
            s4_ += bf_lo(h[j].z) * w[j]; s5_ += bf_hi(h[j].z) * w[j];
            s6_ += bf_lo(h[j].w) * w[j]; s7_ += bf_hi(h[j].w) * w[j];
        }
    }
    for (; e + 4 <= e1; e += 4) {
        int a[4];
#pragma unroll
        for (int j = 0; j < 4; ++j) a[j] = csr[e + j];
        float w[4];
#pragma unroll
        for (int j = 0; j < 4; ++j) w[j] = dis[a[j]];
        uint4 h[4];
#pragma unroll
        for (int j = 0; j < 4; ++j) h[j] = *(const uint4*)(H + (size_t)a[j] * 128 + l * 8);
#pragma unroll
        for (int j = 0; j < 4; ++j) {
            s0_ += bf_lo(h[j].x) * w[j]; s1_ += bf_hi(h[j].x) * w[j];
            s2_ += bf_lo(h[j].y) * w[j]; s3_ += bf_hi(h[j].y) * w[j];
            s4_ += bf_lo(h[j].z) * w[j]; s5_ += bf_hi(h[j].z) * w[j];
            s6_ += bf_lo(h[j].w) * w[j]; s7_ += bf_hi(h[j].w) * w[j];
        }
    }
    for (; e < e1; ++e) {
        const int a = csr[e];
        const float w = dis[a];
        const uint4 h = *(const uint4*)(H + (size_t)a * 128 + l * 8);
        s0_ += bf_lo(h.x)*w; s1_ += bf_hi(h.x)*w;
        s2_ += bf_lo(h.y)*w; s3_ += bf_hi(h.y)*w;
        s4_ += bf_lo(h.z)*w; s5_ += bf_hi(h.z)*w;
        s6_ += bf_lo(h.w)*w; s7_ += bf_hi(h.w)*w;
    }

    const float self = dn * dn;
    const float4 bA = *(const float4*)&bias[l * 8];
    const float4 bB = *(const float4*)&bias[l * 8 + 4];
    float o0 = fmaxf(s0_ * dn + bf_lo(hq.x) * self + bA.x, 0.0f);
    float o1 = fmaxf(s1_ * dn + bf_hi(hq.x) * self + bA.y, 0.0f);
    float o2 = fmaxf(s2_ * dn + bf_lo(hq.y) * self + bA.z, 0.0f);
    float o3 = fmaxf(s3_ * dn + bf_hi(hq.y) * self + bA.w, 0.0f);
    float o4 = fmaxf(s4_ * dn + bf_lo(hq.z) * self + bB.x, 0.0f);
    float o5 = fmaxf(s5_ * dn + bf_hi(hq.z) * self + bB.y, 0.0f);
    float o6 = fmaxf(s6_ * dn + bf_lo(hq.w) * self + bB.z, 0.0f);
    float o7 = fmaxf(s7_ * dn + bf_hi(hq.w) * self + bB.w, 0.0f);

    uint4 o;
    o.x = pack2bf(o0, o1); o.y = pack2bf(o2, o3);
    o.z = pack2bf(o4, o5); o.w = pack2bf(o6, o7);
    *(uint4*)(Out + (size_t)node * 128 + l * 8) = o;
}

// ---------------------------------------------------------------------------
// agg2 over pre-scaled Hs, fused with mean-pool partials (LDS staging +
// sorted-run atomic flush).
// ---------------------------------------------------------------------------
__global__ __launch_bounds__(256) void aggregate_pool(const ushort* __restrict__ H,
                                                      const float* __restrict__ dis,
                                                      const int* __restrict__ rbeg,
                                                      const int* __restrict__ rend,
                                                      const int* __restrict__ csr,
                                                      const float* __restrict__ bias,
                                                      const int* __restrict__ batch,
                                                      float* __restrict__ pooled,
                                                      int n) {
    const int g = threadIdx.x >> 4;
    const int l = threadIdx.x & 15;
    const int node = blockIdx.x * 16 + g;
    const bool valid = node < n;

    float s0_=0.f,s1_=0.f,s2_=0.f,s3_=0.f,s4_=0.f,s5_=0.f,s6_=0.f,s7_=0.f;
    float dn = 0.f;
    const float4 bA = *(const float4*)&bias[l * 8];
    const float4 bB = *(const float4*)&bias[l * 8 + 4];

    if (valid) {
        dn = dis[node];
        const uint4 hq = *(const uint4*)(H + (size_t)node * 128 + l * 8);
        s0_ = bf_lo(hq.x); s1_ = bf_hi(hq.x);
        s2_ = bf_lo(hq.y); s3_ = bf_hi(hq.y);
        s4_ = bf_lo(hq.z); s5_ = bf_hi(hq.z);
        s6_ = bf_lo(hq.w); s7_ = bf_hi(hq.w);

        const int e0 = rbeg[node];
        const int e1 = rend[node];
        int e = e0;
        for (; e + 8 <= e1; e += 8) {
            int a[8];
#pragma unroll
            for (int j = 0; j < 8; ++j) a[j] = csr[e + j];
            uint4 h[8];
#pragma unroll
            for (int j = 0; j < 8; ++j) h[j] = *(const uint4*)(H + (size_t)a[j] * 128 + l * 8);
#pragma unroll
            for (int j = 0; j < 8; ++j) {
                s0_ += bf_lo(h[j].x); s1_ += bf_hi(h[j].x);
                s2_ += bf_lo(h[j].y); s3_ += bf_hi(h[j].y);
                s4_ += bf_lo(h[j].z); s5_ += bf_hi(h[j].z);
                s6_ += bf_lo(h[j].w); s7_ += bf_hi(h[j].w);
            }
        }
        for (; e + 4 <= e1; e += 4) {
            int a[4];
#pragma unroll
            for (int j = 0; j < 4; ++j) a[j] = csr[e + j];
            uint4 h[4];
#pragma unroll
            for (int j = 0; j < 4; ++j) h[j] = *(const uint4*)(H + (size_t)a[j] * 128 + l * 8);
#pragma unroll
            for (int j = 0; j < 4; ++j) {
                s0_ += bf_lo(h[j].x); s1_ += bf_hi(h[j].x);
                s2_ += bf_lo(h[j].y); s3_ += bf_hi(h[j].y);
                s4_ += bf_lo(h[j].z); s5_ += bf_hi(h[j].z);
                s6_ += bf_lo(h[j].w); s7_ += bf_hi(h[j].w);
            }
        }
        for (; e < e1; ++e) {
            const uint4 h = *(const uint4*)(H + (size_t)csr[e] * 128 + l * 8);
            s0_ += bf_lo(h.x); s1_ += bf_hi(h.x);
            s2_ += bf_lo(h.y); s3_ += bf_hi(h.y);
            s4_ += bf_lo(h.z); s5_ += bf_hi(h.z);
            s6_ += bf_lo(h.w); s7_ += bf_hi(h.w);
        }
    }

    const float o0 = fmaxf(s0_ * dn + bA.x, 0.0f);
    const float o1 = fmaxf(s1_ * dn + bA.y, 0.0f);
    const float o2 = fmaxf(s2_ * dn + bA.z, 0.0f);
    const float o3 = fmaxf(s3_ * dn + bA.w, 0.0f);
    const float o4 = fmaxf(s4_ * dn + bB.x, 0.0f);
    const float o5 = fmaxf(s5_ * dn + bB.y, 0.0f);
    const float o6 = fmaxf(s6_ * dn + bB.z, 0.0f);
    const float o7 = fmaxf(s7_ * dn + bB.w, 0.0f);

    __shared__ float x3[16][128];
    __shared__ int bv[16];
    if (valid) {
        float4 va, vb;
        va.x = o0; va.y = o1; va.z = o2; va.w = o3;
        vb.x = o4; vb.y = o5; vb.z = o6; vb.w = o7;
        *(float4*)&x3[g][l * 8]     = va;
        *(float4*)&x3[g][l * 8 + 4] = vb;
        if (l == 0) bv[g] = batch[node];
    } else if (l == 0) {
        bv[g] = -1;
    }
    __syncthreads();
    const int t = threadIdx.x;
    if (t < 128) {
        int cur = bv[0];
        float run = 0.0f;
        for (int r = 0; r < 16; ++r) {
            const int b = bv[r];
            if (b < 0) break;
            if (b != cur) {
                if (run != 0.0f) atomicAdd(&pooled[(size_t)cur * 128 + t], run);
                cur = b; run = 0.0f;
            }
            run += x3[r][t];
        }
        if (cur >= 0 && run != 0.0f) atomicAdd(&pooled[(size_t)cur * 128 + t], run);
    }
}

// ---------------------------------------------------------------------------
// Pool finalize: counts via binary search on sorted batch, divide, 128x10.
// ---------------------------------------------------------------------------
__global__ __launch_bounds__(128) void pool_finalize(const float* __restrict__ pooled,
                                                     const int* __restrict__ batch,
                                                     const float* __restrict__ lw,
                                                     const float* __restrict__ lb,
                                                     float* __restrict__ out, int n) {
    const int g = blockIdx.x;
    const int t = threadIdx.x;
    int lo = 0, hi = n;
    while (lo < hi) { int mid = (lo + hi) >> 1; if (batch[mid] < g) lo = mid + 1; else hi = mid; }
    const int s = lo;
    hi = n;
    while (lo < hi) { int mid = (lo + hi) >> 1; if (batch[mid] < g + 1) lo = mid + 1; else hi = mid; }
    const float c = fmaxf((float)(lo - s), 1.0f);

    __shared__ float pl[128];
    pl[t] = pooled[(size_t)g * 128 + t] / c;
    __syncthreads();
    if (t < 10) {
        float acc = lb[t];
#pragma unroll 16
        for (int d = 0; d < 128; ++d) acc += pl[d] * lw[d * 10 + t];
        out[g * 10 + t] = acc;
    }
}

// ---------------------------------------------------------------------------
extern "C" void kernel_launch(void* const* d_in, const int* in_sizes, int n_in,
                              void* d_out, int out_size, void* d_ws, size_t ws_size,
                              hipStream_t stream) {
    const int*   tokens = (const int*)d_in[0];
    const int*   eidx   = (const int*)d_in[1];
    const int*   batch  = (const int*)d_in[2];
    const float* emb    = (const float*)d_in[3];
    const float* w1     = (const float*)d_in[4];
    const float* b1     = (const float*)d_in[5];
    const float* w2     = (const float*)d_in[6];
    const float* b2     = (const float*)d_in[7];
    const float* lw     = (const float*)d_in[8];
    const float* lbv    = (const float*)d_in[9];

    const int N = in_sizes[0];
    const int E = in_sizes[1] / 2;
    const int G = out_size / 10;
    const int* src = eidx;
    const int* dst = eidx + E;
    const int NB = (N + 255) >> 8;
    const int GB = (N + 127) / 128;

    char* p = (char*)d_ws;
    auto alloc = [&](size_t bytes) { void* r = (void*)p; p += (bytes + 255) & ~(size_t)255; return r; };
    float*  dis    = (float*)alloc((size_t)N * 4);
    int*    rbeg   = (int*)  alloc((size_t)N * 4);
    int*    rend   = (int*)  alloc((size_t)N * 4);
    int*    bcur   = (int*)  alloc(256 * 4);
    float*  pooled = (float*)alloc((size_t)G * 128 * 4);
    uint*   bstage = (uint*) alloc((size_t)NB * CAP * 4);
    int*    csr    = (int*)  alloc((size_t)NB * CAP * 4);
    ushort* W1t    = (ushort*)alloc(16384 * 2);
    ushort* W2t    = (ushort*)alloc(16384 * 2);
    ushort* A      = (ushort*)alloc((size_t)N * 128 * 2);   // H / Hs2 (bf16)
    ushort* B      = (ushort*)alloc((size_t)N * 128 * 2);   // X2 (bf16)

    const int PZ4 = (G * 128) / 4;                 // pooled int4 count
    const int PZB = (PZ4 + 255) / 256;             // blocks to zero pooled
    const int EB  = (E + EPB - 1) / EPB;

    // L0: bcur zero + weight convert
    init0<<<129, 256, 0, stream>>>(bcur, w1, w2, W1t, W2t);
    // L1: edge scatter into buckets
    bucket_scatter<<<EB, 256, 0, stream>>>(src, dst, bcur, bstage, E, NB);
    // L2: csr_build (blocks 0..NB) | gemm1 unscaled (NB..NB+GB) | pooled zero
    csr_gemm1_fused<<<NB + GB + PZB, 256, 0, stream>>>(bstage, bcur, dis, rbeg, rend, csr,
                                                       tokens, emb, W1t, A,
                                                       (int4*)pooled, PZ4, N, NB, GB);
    // L3: X2 = relu(dn*sum(H[src]*dis[src]) + H*dn^2 + b1)
    aggregate_w<<<(N + 15) / 16, 256, 0, stream>>>(A, dis, rbeg, rend, csr, b1, B, N);
    // L4: Hs2 = (X2 @ W2) * dis
    gemm2_kernel<<<GB, 256, 0, stream>>>(B, W2t, dis, A, N);
    // L5: agg2 (pure sum) + pooled partials
    aggregate_pool<<<(N + 15) / 16, 256, 0, stream>>>(A, dis, rbeg, rend, csr, b2, batch, pooled, N);
    // L6: finalize
    pool_finalize<<<G, 128, 0, stream>>>(pooled, batch, lw, lbv, (float*)d_out, N);
}